// Round 10
// baseline (1086.170 us; speedup 1.0000x reference)
//
#include <hip/hip_runtime.h>

// B=64, T=64 -> GEMM M=4096, N=2048, K=2048 ; tdBN ; LIF scan. Full f64
// results (r1/r4/r6/r7/r8: absmax == 0.0). Round 10: DIAGNOSTIC A/B.
// Three schedules (r7/r8/r9) all sit at 76-79% of the assumed 437us
// f64-MFMA floor -> suspect the floor itself (MFMA f64 slower than 64cy/
// SIMD, or f64-load downclock). Kernel A (mfma_ceiling) = r8 geometry with
// NO memory system: pure MFMA issue, operands opaque via asm. Kernel B =
// r8's verified 575us GEMM, authoritative (overwrites H fully).
// Pre-committed decision: ceiling 430-470us -> pipeline is the gap, keep
// optimizing; >=530us -> r8 is >=95% of device ceiling -> roofline.

typedef double double4v __attribute__((ext_vector_type(4)));

#define KDIM 2048
#define NDIM 2048
#define BKt  32
#define LROW 128

// ---------------- Kernel A: pure f64-MFMA rate probe ----------------
__global__ __launch_bounds__(256, 2) void mfma_ceiling(double* __restrict__ D)
{
    const int tid  = threadIdx.x;
    const int lane = tid & 63;

    double fa0 = 1.0 + lane * 1e-9, fa1 = 1.1 + lane * 1e-9;
    double fa2 = 1.2 + lane * 1e-9, fa3 = 1.3 + lane * 1e-9;
    double fb0 = 0.5 + lane * 1e-9, fb1 = 0.6 + lane * 1e-9;
    double fb2 = 0.7 + lane * 1e-9, fb3 = 0.8 + lane * 1e-9;
    asm volatile("" : "+v"(fa0)); asm volatile("" : "+v"(fa1));
    asm volatile("" : "+v"(fa2)); asm volatile("" : "+v"(fa3));
    asm volatile("" : "+v"(fb0)); asm volatile("" : "+v"(fb1));
    asm volatile("" : "+v"(fb2)); asm volatile("" : "+v"(fb3));

    double4v acc[4][4];
    #pragma unroll
    for (int t = 0; t < 4; ++t)
        #pragma unroll
        for (int u = 0; u < 4; ++u)
            acc[t][u] = (double4v){0.0, 0.0, 0.0, 0.0};

    // 64 tiles x 8 ks x 16 MFMA = 8192 MFMA per wave (same as r8's GEMM)
    for (int t = 0; t < 64; ++t) {
        #pragma unroll
        for (int ks = 0; ks < 8; ++ks) {
#define MM(ti, ui, av, bv) \
            acc[ti][ui] = __builtin_amdgcn_mfma_f64_16x16x4f64(av, bv, acc[ti][ui], 0, 0, 0);
            MM(0,0,fa0,fb0) MM(0,1,fa0,fb1) MM(0,2,fa0,fb2) MM(0,3,fa0,fb3)
            MM(1,0,fa1,fb0) MM(1,1,fa1,fb1) MM(1,2,fa1,fb2) MM(1,3,fa1,fb3)
            MM(2,0,fa2,fb0) MM(2,1,fa2,fb1) MM(2,2,fa2,fb2) MM(2,3,fa2,fb3)
            MM(3,0,fa3,fb0) MM(3,1,fa3,fb1) MM(3,2,fa3,fb2) MM(3,3,fa3,fb3)
#undef MM
        }
    }

    double s = 0.0;
    #pragma unroll
    for (int t = 0; t < 4; ++t)
        #pragma unroll
        for (int u = 0; u < 4; ++u)
            #pragma unroll
            for (int v = 0; v < 4; ++v) s += acc[t][u][v];
    D[(size_t)(blockIdx.y * gridDim.x + blockIdx.x) * 256 + tid] = s;
}

// ---------------- Kernel B: r8's verified GEMM (authoritative) ----------------
__global__ __launch_bounds__(256, 2) void gemm_f64_mfma3(
    const float* __restrict__ X,   // (4096, 2048)
    const float* __restrict__ W,   // (2048, 2048)
    const float* __restrict__ bias,
    double* __restrict__ H)        // (4096, 2048)
{
    constexpr int NT = KDIM / BKt;           // 64
    __shared__ float As[2][BKt][LROW];       // 32 KB
    __shared__ float Bs[2][BKt][LROW];       // 32 KB

    const int tid  = threadIdx.x;
    const int lane = tid & 63;
    const int wid  = tid >> 6;
    const int lf = lane & 15, lq = lane >> 4;
    const int bm = blockIdx.x * 128, bn = blockIdx.y * 128;
    const int wr = wid >> 1, wc = wid & 1;      // wave -> 64x64 quadrant

    // layout self-calibration probe (r7-verified)
    double4v pd = (double4v){0.0, 0.0, 0.0, 0.0};
    pd = __builtin_amdgcn_mfma_f64_16x16x4f64(
        (double)(lane + 1), (double)((lane + 1) * (lane + 1)), pd, 0, 0, 0);
    int winner = -1;
    #pragma unroll
    for (int h = 0; h < 16; ++h) {
        const int c1 = h & 1, c2 = (h >> 1) & 1, cd = h >> 2;
        bool ok = true;
        #pragma unroll
        for (int v = 0; v < 4; ++v) {
            const int r16 = (cd == 0) ? 4 * lq + v : (cd == 1) ? lf
                          : (cd == 2) ? lq + 4 * v : lf;
            const int c16 = (cd == 0) ? lf : (cd == 1) ? 4 * lq + v
                          : (cd == 2) ? lf : lq + 4 * v;
            double s = 0.0;
            #pragma unroll
            for (int k = 0; k < 4; ++k) {
                const int i1 = c1 ? (r16 + 16 * k) : (4 * r16 + k);
                const int i2 = c2 ? (c16 + 16 * k) : (4 * c16 + k);
                s += (double)(i1 + 1) * (double)((i2 + 1) * (i2 + 1));
            }
            ok = ok && (pd[v] == s);
        }
        if (__ballot(ok) == ~0ull && winner < 0) winner = h;
    }
    if (winner < 0) winner = 0;
    const int selA = winner & 1, selB = (winner >> 1) & 1, selD = winner >> 2;

    const int rlA = selA ? lf : (lane >> 2);
    const int klA = selA ? lq : (lane & 3);
    const int rlB = selB ? lf : (lane >> 2);
    const int klB = selB ? lq : (lane & 3);
    const int baseA = klA * LROW + wr * 64 + rlA * 4;
    const int baseB = klB * LROW + wc * 64 + rlB * 4;

    const int arow = tid >> 1;            // 0..127
    const int kofs = (tid & 1) * 16;      // 0 or 16
    const float* xa = X + (size_t)(bm + arow) * KDIM + kofs;
    const float* wa = W + (size_t)(bn + arow) * KDIM + kofs;
    const int r6  = arow & 63;
    const int pos = (arow >> 6) * 64 + (r6 & 15) * 4 + (r6 >> 4);

#define STAGE(buf, A0, A1, A2, A3, B0, B1, B2, B3) do { \
    As[buf][kofs+ 0][pos]=A0.x; As[buf][kofs+ 1][pos]=A0.y; \
    As[buf][kofs+ 2][pos]=A0.z; As[buf][kofs+ 3][pos]=A0.w; \
    As[buf][kofs+ 4][pos]=A1.x; As[buf][kofs+ 5][pos]=A1.y; \
    As[buf][kofs+ 6][pos]=A1.z; As[buf][kofs+ 7][pos]=A1.w; \
    As[buf][kofs+ 8][pos]=A2.x; As[buf][kofs+ 9][pos]=A2.y; \
    As[buf][kofs+10][pos]=A2.z; As[buf][kofs+11][pos]=A2.w; \
    As[buf][kofs+12][pos]=A3.x; As[buf][kofs+13][pos]=A3.y; \
    As[buf][kofs+14][pos]=A3.z; As[buf][kofs+15][pos]=A3.w; \
    Bs[buf][kofs+ 0][pos]=B0.x; Bs[buf][kofs+ 1][pos]=B0.y; \
    Bs[buf][kofs+ 2][pos]=B0.z; Bs[buf][kofs+ 3][pos]=B0.w; \
    Bs[buf][kofs+ 4][pos]=B1.x; Bs[buf][kofs+ 5][pos]=B1.y; \
    Bs[buf][kofs+ 6][pos]=B1.z; Bs[buf][kofs+ 7][pos]=B1.w; \
    Bs[buf][kofs+ 8][pos]=B2.x; Bs[buf][kofs+ 9][pos]=B2.y; \
    Bs[buf][kofs+10][pos]=B2.z; Bs[buf][kofs+11][pos]=B2.w; \
    Bs[buf][kofs+12][pos]=B3.x; Bs[buf][kofs+13][pos]=B3.y; \
    Bs[buf][kofs+14][pos]=B3.z; Bs[buf][kofs+15][pos]=B3.w; } while (0)

    double4v acc[4][4];
    #pragma unroll
    for (int t = 0; t < 4; ++t)
        #pragma unroll
        for (int u = 0; u < 4; ++u)
            acc[t][u] = (double4v){0.0, 0.0, 0.0, 0.0};

    {   // prologue: stage k-tile 0
        float4 a0 = *(const float4*)(xa);
        float4 a1 = *(const float4*)(xa + 4);
        float4 a2 = *(const float4*)(xa + 8);
        float4 a3 = *(const float4*)(xa + 12);
        float4 b0 = *(const float4*)(wa);
        float4 b1 = *(const float4*)(wa + 4);
        float4 b2 = *(const float4*)(wa + 8);
        float4 b3 = *(const float4*)(wa + 12);
        STAGE(0, a0, a1, a2, a3, b0, b1, b2, b3);
    }
    __syncthreads();

    int cur = 0;
    for (int t = 0; t < NT; ++t) {
        const bool more = (t + 1) < NT;
        float4 pa0, pa1, pa2, pa3, pb0, pb1, pb2, pb3;
        if (more) {
            const int k0 = (t + 1) * BKt;
            pa0 = *(const float4*)(xa + k0);
            pa1 = *(const float4*)(xa + k0 + 4);
            pa2 = *(const float4*)(xa + k0 + 8);
            pa3 = *(const float4*)(xa + k0 + 12);
            pb0 = *(const float4*)(wa + k0);
            pb1 = *(const float4*)(wa + k0 + 4);
            pb2 = *(const float4*)(wa + k0 + 8);
            pb3 = *(const float4*)(wa + k0 + 12);
        }

        const float* Af = &As[cur][0][0];
        const float* Bf = &Bs[cur][0][0];
        #pragma unroll
        for (int ks = 0; ks < 8; ++ks) {
            const float4 fa = *(const float4*)&Af[4 * ks * LROW + baseA];
            const float4 fb = *(const float4*)&Bf[4 * ks * LROW + baseB];
            const double fa0 = fa.x, fa1 = fa.y, fa2 = fa.z, fa3 = fa.w;
            const double fb0 = fb.x, fb1 = fb.y, fb2 = fb.z, fb3 = fb.w;
#define MM(ti, ui, av, bv) \
            acc[ti][ui] = __builtin_amdgcn_mfma_f64_16x16x4f64(av, bv, acc[ti][ui], 0, 0, 0);
            MM(0,0,fa0,fb0) MM(0,1,fa0,fb1) MM(0,2,fa0,fb2) MM(0,3,fa0,fb3)
            MM(1,0,fa1,fb0) MM(1,1,fa1,fb1) MM(1,2,fa1,fb2) MM(1,3,fa1,fb3)
            MM(2,0,fa2,fb0) MM(2,1,fa2,fb1) MM(2,2,fa2,fb2) MM(2,3,fa2,fb3)
            MM(3,0,fa3,fb0) MM(3,1,fa3,fb1) MM(3,2,fa3,fb2) MM(3,3,fa3,fb3)
#undef MM
        }

        if (more) STAGE(cur ^ 1, pa0, pa1, pa2, pa3, pb0, pb1, pb2, pb3);
        __syncthreads();
        cur ^= 1;
    }

    #pragma unroll
    for (int v = 0; v < 4; ++v) {
        const int r16 = (selD == 0) ? 4 * lq + v : (selD == 1) ? lf
                      : (selD == 2) ? lq + 4 * v : lf;
        const int c16 = (selD == 0) ? lf : (selD == 1) ? 4 * lq + v
                      : (selD == 2) ? lf : lq + 4 * v;
        #pragma unroll
        for (int t = 0; t < 4; ++t) {
            const int row = bm + wr * 64 + 16 * t + r16;
            #pragma unroll
            for (int u = 0; u < 4; ++u) {
                const int col = bn + wc * 64 + 16 * u + c16;
                H[(size_t)row * NDIM + col] = acc[t][u][v] + (double)bias[col];
            }
        }
    }
}

// ---------------- epilogue chain (unchanged, verified) ----------------
__global__ __launch_bounds__(256) void bn_partial(
    const double* __restrict__ H, double* __restrict__ psum, double* __restrict__ psq)
{
    constexpr int N = 2048, ROWS = 128;
    const int o  = blockIdx.x * 256 + threadIdx.x;
    const int t0 = blockIdx.y * ROWS;
    double s = 0.0, q = 0.0;
    for (int r = 0; r < ROWS; ++r) {
        double h = H[(size_t)(t0 + r) * N + o];
        s += h;
        q = fma(h, h, q);
    }
    psum[(size_t)blockIdx.y * N + o] = s;
    psq [(size_t)blockIdx.y * N + o] = q;
}

__global__ void bn_finalize(const double* __restrict__ psum, const double* __restrict__ psq,
                            double* __restrict__ meanv, double* __restrict__ varv)
{
    constexpr int N = 2048, CH = 32;
    const int o = blockIdx.x * blockDim.x + threadIdx.x;
    double s = 0.0, q = 0.0;
    for (int c = 0; c < CH; ++c) {
        s += psum[(size_t)c * N + o];
        q += psq [(size_t)c * N + o];
    }
    const double m = s / 4096.0;
    meanv[o] = m;
    varv[o]  = q / 4096.0 - m * m;
}

__global__ __launch_bounds__(256) void bn_lif(
    const double* __restrict__ H,
    const double* __restrict__ meanv, const double* __restrict__ varv,
    const float* __restrict__ gamma, const float* __restrict__ beta_bn,
    const float* __restrict__ mem_init,
    const float* __restrict__ lif_beta, const float* __restrict__ thr,
    float* __restrict__ out)
{
    constexpr int T = 64, F = 2048;
    const int gid = blockIdx.x * 256 + threadIdx.x;
    const int o = gid & (F - 1);
    const int b = gid >> 11;

    const double m      = meanv[o];
    const double invstd = 1.0 / sqrt(varv[o] + 1e-5);
    const double sc     = invstd * (double)gamma[o];
    const double sh     = (double)beta_bn[o];
    const double beta_c = fmin(fmax((double)lif_beta[0], 0.0), 1.0);
    const double th     = (double)thr[0];

    double mem = (double)mem_init[gid];
    const double* hp = H   + (size_t)b * T * F + o;
    float*        op = out + (size_t)b * T * F + o;

    for (int t = 0; t < T; ++t) {
        const double h  = hp[(size_t)t * F];
        const double xt = (h - m) * sc + sh;
        const double reset = (mem > th) ? th : 0.0;
        mem = fma(beta_c, mem, xt) - reset;
        op[(size_t)t * F] = (mem > th) ? 1.0f : 0.0f;
    }
}

extern "C" void kernel_launch(void* const* d_in, const int* in_sizes, int n_in,
                              void* d_out, int out_size, void* d_ws, size_t ws_size,
                              hipStream_t stream)
{
    const float* x        = (const float*)d_in[0];
    const float* mem_init = (const float*)d_in[1];
    const float* W        = (const float*)d_in[2];
    const float* b        = (const float*)d_in[3];
    const float* gamma    = (const float*)d_in[4];
    const float* beta_bn  = (const float*)d_in[5];
    const float* lif_beta = (const float*)d_in[6];
    const float* thr      = (const float*)d_in[7];
    float* out = (float*)d_out;

    char* ws = (char*)d_ws;
    double* H     = (double*)ws;                                  // 64 MiB
    double* psum  = (double*)(ws + (size_t)67108864);
    double* psq   = (double*)(ws + (size_t)67108864 + 524288);
    double* meanv = (double*)(ws + (size_t)67108864 + 2 * 524288);
    double* varv  = meanv + 2048;

    // A/B: mfma_ceiling writes scratch into H; gemm overwrites all of H.
    mfma_ceiling  <<<dim3(32, 16), 256, 0, stream>>>(H);
    gemm_f64_mfma3<<<dim3(32, 16), 256, 0, stream>>>(x, W, b, H);
    bn_partial    <<<dim3(8, 32),  256, 0, stream>>>(H, psum, psq);
    bn_finalize   <<<8,            256, 0, stream>>>(psum, psq, meanv, varv);
    bn_lif        <<<512,          256, 0, stream>>>(H, meanv, varv, gamma, beta_bn,
                                                     mem_init, lif_beta, thr, out);
}

// Round 11
// 662.507 us; speedup vs baseline: 1.6395x; 1.6395x over previous
//
#include <hip/hip_runtime.h>

// B=64, T=64 -> GEMM M=4096, N=2048, K=2048 ; tdBN ; LIF scan. Full f64
// results (r1/r4/r6/r7/r8/r10: absmax == 0.0). Round 11: r8's verified
// GEMM (574us) + intra-tile software pipeline. r10 measured the pure
// f64-MFMA ceiling at ~450us (76.4 TF) => 124us schedule overhead. r9
// falsified cross-block barrier correlation; surviving theory = per-group
// lgkm-wait exposure + end-of-tile write bunching. Changes (reorder only):
//   - fragments register-prefetched one ks-group ahead (ds_read issued
//     1024 MFMA-cycles before use -> zero exposed lgkm wait)
//   - the 32 staging ds_writes spread into groups 2..5 (8 per group),
//     leaving groups 6..7 write-free so the lgkm drain hides under MFMAs
// Layouts, calibration probe, epilogue chain: verbatim r8.

typedef double double4v __attribute__((ext_vector_type(4)));

#define KDIM 2048
#define NDIM 2048
#define BKt  32
#define LROW 128

__global__ __launch_bounds__(256, 2) void gemm_f64_mfma5(
    const float* __restrict__ X,   // (4096, 2048)
    const float* __restrict__ W,   // (2048, 2048)
    const float* __restrict__ bias,
    double* __restrict__ H)        // (4096, 2048)
{
    constexpr int NT = KDIM / BKt;           // 64
    __shared__ float As[2][BKt][LROW];       // 32 KB
    __shared__ float Bs[2][BKt][LROW];       // 32 KB

    const int tid  = threadIdx.x;
    const int lane = tid & 63;
    const int wid  = tid >> 6;
    const int lf = lane & 15, lq = lane >> 4;
    const int bm = blockIdx.x * 128, bn = blockIdx.y * 128;
    const int wr = wid >> 1, wc = wid & 1;      // wave -> 64x64 quadrant

    // ---------------- layout self-calibration probe (r7-verified) ----------------
    double4v pd = (double4v){0.0, 0.0, 0.0, 0.0};
    pd = __builtin_amdgcn_mfma_f64_16x16x4f64(
        (double)(lane + 1), (double)((lane + 1) * (lane + 1)), pd, 0, 0, 0);
    int winner = -1;
    #pragma unroll
    for (int h = 0; h < 16; ++h) {
        const int c1 = h & 1, c2 = (h >> 1) & 1, cd = h >> 2;
        bool ok = true;
        #pragma unroll
        for (int v = 0; v < 4; ++v) {
            const int r16 = (cd == 0) ? 4 * lq + v : (cd == 1) ? lf
                          : (cd == 2) ? lq + 4 * v : lf;
            const int c16 = (cd == 0) ? lf : (cd == 1) ? 4 * lq + v
                          : (cd == 2) ? lf : lq + 4 * v;
            double s = 0.0;
            #pragma unroll
            for (int k = 0; k < 4; ++k) {
                const int i1 = c1 ? (r16 + 16 * k) : (4 * r16 + k);
                const int i2 = c2 ? (c16 + 16 * k) : (4 * c16 + k);
                s += (double)(i1 + 1) * (double)((i2 + 1) * (i2 + 1));
            }
            ok = ok && (pd[v] == s);
        }
        if (__ballot(ok) == ~0ull && winner < 0) winner = h;
    }
    if (winner < 0) winner = 0;
    const int selA = winner & 1, selB = (winner >> 1) & 1, selD = winner >> 2;

    const int rlA = selA ? lf : (lane >> 2);
    const int klA = selA ? lq : (lane & 3);
    const int rlB = selB ? lf : (lane >> 2);
    const int klB = selB ? lq : (lane & 3);
    const int baseA = klA * LROW + wr * 64 + rlA * 4;
    const int baseB = klB * LROW + wc * 64 + rlB * 4;

    // ---------------- staging addresses ----------------
    const int arow = tid >> 1;            // 0..127
    const int kofs = (tid & 1) * 16;      // 0 or 16
    const float* xa = X + (size_t)(bm + arow) * KDIM + kofs;
    const float* wa = W + (size_t)(bn + arow) * KDIM + kofs;
    const int r6  = arow & 63;
    const int pos = (arow >> 6) * 64 + (r6 & 15) * 4 + (r6 >> 4);

#define STAGE0(A0, A1, A2, A3, B0, B1, B2, B3) do { \
    As[0][kofs+ 0][pos]=A0.x; As[0][kofs+ 1][pos]=A0.y; \
    As[0][kofs+ 2][pos]=A0.z; As[0][kofs+ 3][pos]=A0.w; \
    As[0][kofs+ 4][pos]=A1.x; As[0][kofs+ 5][pos]=A1.y; \
    As[0][kofs+ 6][pos]=A1.z; As[0][kofs+ 7][pos]=A1.w; \
    As[0][kofs+ 8][pos]=A2.x; As[0][kofs+ 9][pos]=A2.y; \
    As[0][kofs+10][pos]=A2.z; As[0][kofs+11][pos]=A2.w; \
    As[0][kofs+12][pos]=A3.x; As[0][kofs+13][pos]=A3.y; \
    As[0][kofs+14][pos]=A3.z; As[0][kofs+15][pos]=A3.w; \
    Bs[0][kofs+ 0][pos]=B0.x; Bs[0][kofs+ 1][pos]=B0.y; \
    Bs[0][kofs+ 2][pos]=B0.z; Bs[0][kofs+ 3][pos]=B0.w; \
    Bs[0][kofs+ 4][pos]=B1.x; Bs[0][kofs+ 5][pos]=B1.y; \
    Bs[0][kofs+ 6][pos]=B1.z; Bs[0][kofs+ 7][pos]=B1.w; \
    Bs[0][kofs+ 8][pos]=B2.x; Bs[0][kofs+ 9][pos]=B2.y; \
    Bs[0][kofs+10][pos]=B2.z; Bs[0][kofs+11][pos]=B2.w; \
    Bs[0][kofs+12][pos]=B3.x; Bs[0][kofs+13][pos]=B3.y; \
    Bs[0][kofs+14][pos]=B3.z; Bs[0][kofs+15][pos]=B3.w; } while (0)

    double4v acc[4][4];
    #pragma unroll
    for (int t = 0; t < 4; ++t)
        #pragma unroll
        for (int u = 0; u < 4; ++u)
            acc[t][u] = (double4v){0.0, 0.0, 0.0, 0.0};

    {   // prologue: stage k-tile 0
        float4 a0 = *(const float4*)(xa);
        float4 a1 = *(const float4*)(xa + 4);
        float4 a2 = *(const float4*)(xa + 8);
        float4 a3 = *(const float4*)(xa + 12);
        float4 b0 = *(const float4*)(wa);
        float4 b1 = *(const float4*)(wa + 4);
        float4 b2 = *(const float4*)(wa + 8);
        float4 b3 = *(const float4*)(wa + 12);
        STAGE0(a0, a1, a2, a3, b0, b1, b2, b3);
    }
    __syncthreads();

#define MM(ti, ui, av, bv) \
    acc[ti][ui] = __builtin_amdgcn_mfma_f64_16x16x4f64(av, bv, acc[ti][ui], 0, 0, 0);

    // one ks-group: prefetch next group's fragments, 16 MFMAs, spread writes
#define GRP(g, WR) { \
    float4 fa_n = fa_c, fb_n = fb_c; \
    if ((g) < 7) { \
        fa_n = *(const float4*)&Af[4 * ((g) + 1) * LROW + baseA]; \
        fb_n = *(const float4*)&Bf[4 * ((g) + 1) * LROW + baseB]; \
    } \
    { \
        const double a0 = fa_c.x, a1 = fa_c.y, a2 = fa_c.z, a3 = fa_c.w; \
        const double b0 = fb_c.x, b1 = fb_c.y, b2 = fb_c.z, b3 = fb_c.w; \
        MM(0,0,a0,b0) MM(0,1,a0,b1) MM(0,2,a0,b2) MM(0,3,a0,b3) \
        MM(1,0,a1,b0) MM(1,1,a1,b1) MM(1,2,a1,b2) MM(1,3,a1,b3) \
        MM(2,0,a2,b0) MM(2,1,a2,b1) MM(2,2,a2,b2) MM(2,3,a2,b3) \
        MM(3,0,a3,b0) MM(3,1,a3,b1) MM(3,2,a3,b2) MM(3,3,a3,b3) \
    } \
    WR; \
    fa_c = fa_n; fb_c = fb_n; }

#define WRA(q0, V) \
    As[nxt][kofs + (q0) + 0][pos] = V.x; As[nxt][kofs + (q0) + 1][pos] = V.y; \
    As[nxt][kofs + (q0) + 2][pos] = V.z; As[nxt][kofs + (q0) + 3][pos] = V.w;
#define WRB(q0, V) \
    Bs[nxt][kofs + (q0) + 0][pos] = V.x; Bs[nxt][kofs + (q0) + 1][pos] = V.y; \
    Bs[nxt][kofs + (q0) + 2][pos] = V.z; Bs[nxt][kofs + (q0) + 3][pos] = V.w;

    int cur = 0;
    for (int t = 0; t < NT; ++t) {
        const bool more = (t + 1) < NT;
        const int nxt = cur ^ 1;
        float4 pa0, pa1, pa2, pa3, pb0, pb1, pb2, pb3;
        if (more) {
            const int k0 = (t + 1) * BKt;
            pa0 = *(const float4*)(xa + k0);
            pa1 = *(const float4*)(xa + k0 + 4);
            pa2 = *(const float4*)(xa + k0 + 8);
            pa3 = *(const float4*)(xa + k0 + 12);
            pb0 = *(const float4*)(wa + k0);
            pb1 = *(const float4*)(wa + k0 + 4);
            pb2 = *(const float4*)(wa + k0 + 8);
            pb3 = *(const float4*)(wa + k0 + 12);
        }

        const float* Af = &As[cur][0][0];
        const float* Bf = &Bs[cur][0][0];
        float4 fa_c = *(const float4*)&Af[baseA];
        float4 fb_c = *(const float4*)&Bf[baseB];

        GRP(0, )
        GRP(1, )
        GRP(2, if (more) { WRA(0,  pa0) WRB(0,  pb0) })
        GRP(3, if (more) { WRA(4,  pa1) WRB(4,  pb1) })
        GRP(4, if (more) { WRA(8,  pa2) WRB(8,  pb2) })
        GRP(5, if (more) { WRA(12, pa3) WRB(12, pb3) })
        GRP(6, )
        GRP(7, )

        __syncthreads();
        cur = nxt;
    }
#undef GRP
#undef WRA
#undef WRB
#undef MM

    // ---------------- epilogue under winning D-layout (r7-verified) ----------------
    #pragma unroll
    for (int v = 0; v < 4; ++v) {
        const int r16 = (selD == 0) ? 4 * lq + v : (selD == 1) ? lf
                      : (selD == 2) ? lq + 4 * v : lf;
        const int c16 = (selD == 0) ? lf : (selD == 1) ? 4 * lq + v
                      : (selD == 2) ? lf : lq + 4 * v;
        #pragma unroll
        for (int t = 0; t < 4; ++t) {
            const int row = bm + wr * 64 + 16 * t + r16;
            #pragma unroll
            for (int u = 0; u < 4; ++u) {
                const int col = bn + wc * 64 + 16 * u + c16;
                H[(size_t)row * NDIM + col] = acc[t][u][v] + (double)bias[col];
            }
        }
    }
}

// ---------------- epilogue chain (unchanged, verified) ----------------
__global__ __launch_bounds__(256) void bn_partial(
    const double* __restrict__ H, double* __restrict__ psum, double* __restrict__ psq)
{
    constexpr int N = 2048, ROWS = 128;
    const int o  = blockIdx.x * 256 + threadIdx.x;
    const int t0 = blockIdx.y * ROWS;
    double s = 0.0, q = 0.0;
    for (int r = 0; r < ROWS; ++r) {
        double h = H[(size_t)(t0 + r) * N + o];
        s += h;
        q = fma(h, h, q);
    }
    psum[(size_t)blockIdx.y * N + o] = s;
    psq [(size_t)blockIdx.y * N + o] = q;
}

__global__ void bn_finalize(const double* __restrict__ psum, const double* __restrict__ psq,
                            double* __restrict__ meanv, double* __restrict__ varv)
{
    constexpr int N = 2048, CH = 32;
    const int o = blockIdx.x * blockDim.x + threadIdx.x;
    double s = 0.0, q = 0.0;
    for (int c = 0; c < CH; ++c) {
        s += psum[(size_t)c * N + o];
        q += psq [(size_t)c * N + o];
    }
    const double m = s / 4096.0;
    meanv[o] = m;
    varv[o]  = q / 4096.0 - m * m;
}

__global__ __launch_bounds__(256) void bn_lif(
    const double* __restrict__ H,
    const double* __restrict__ meanv, const double* __restrict__ varv,
    const float* __restrict__ gamma, const float* __restrict__ beta_bn,
    const float* __restrict__ mem_init,
    const float* __restrict__ lif_beta, const float* __restrict__ thr,
    float* __restrict__ out)
{
    constexpr int T = 64, F = 2048;
    const int gid = blockIdx.x * 256 + threadIdx.x;
    const int o = gid & (F - 1);
    const int b = gid >> 11;

    const double m      = meanv[o];
    const double invstd = 1.0 / sqrt(varv[o] + 1e-5);
    const double sc     = invstd * (double)gamma[o];
    const double sh     = (double)beta_bn[o];
    const double beta_c = fmin(fmax((double)lif_beta[0], 0.0), 1.0);
    const double th     = (double)thr[0];

    double mem = (double)mem_init[gid];
    const double* hp = H   + (size_t)b * T * F + o;
    float*        op = out + (size_t)b * T * F + o;

    for (int t = 0; t < T; ++t) {
        const double h  = hp[(size_t)t * F];
        const double xt = (h - m) * sc + sh;
        const double reset = (mem > th) ? th : 0.0;
        mem = fma(beta_c, mem, xt) - reset;
        op[(size_t)t * F] = (mem > th) ? 1.0f : 0.0f;
    }
}

extern "C" void kernel_launch(void* const* d_in, const int* in_sizes, int n_in,
                              void* d_out, int out_size, void* d_ws, size_t ws_size,
                              hipStream_t stream)
{
    const float* x        = (const float*)d_in[0];
    const float* mem_init = (const float*)d_in[1];
    const float* W        = (const float*)d_in[2];
    const float* b        = (const float*)d_in[3];
    const float* gamma    = (const float*)d_in[4];
    const float* beta_bn  = (const float*)d_in[5];
    const float* lif_beta = (const float*)d_in[6];
    const float* thr      = (const float*)d_in[7];
    float* out = (float*)d_out;

    char* ws = (char*)d_ws;
    double* H     = (double*)ws;                                  // 64 MiB
    double* psum  = (double*)(ws + (size_t)67108864);
    double* psq   = (double*)(ws + (size_t)67108864 + 524288);
    double* meanv = (double*)(ws + (size_t)67108864 + 2 * 524288);
    double* varv  = meanv + 2048;

    gemm_f64_mfma5<<<dim3(32, 16), 256, 0, stream>>>(x, W, b, H);
    bn_partial    <<<dim3(8, 32),  256, 0, stream>>>(H, psum, psq);
    bn_finalize   <<<8,            256, 0, stream>>>(psum, psq, meanv, varv);
    bn_lif        <<<512,          256, 0, stream>>>(H, meanv, varv, gamma, beta_bn,
                                                     mem_init, lif_beta, thr, out);
}